// Round 10
// baseline (879.607 us; speedup 1.0000x reference)
//
#include <hip/hip_runtime.h>
#include <hip/hip_bf16.h>

typedef __attribute__((ext_vector_type(8))) short bf16x8;
typedef __attribute__((ext_vector_type(4))) float f32x4;
typedef __attribute__((ext_vector_type(4))) unsigned u32x4;

#define CDIM 1024
#define DDIM 1024
#define TDIM 1024
#define BK 32

__device__ __forceinline__ unsigned cvt_pk_bf16(float a, float b) {
    unsigned r;
    asm("v_cvt_pk_bf16_f32 %0, %1, %2" : "=v"(r) : "v"(a), "v"(b));
    return r;
}

// out[b,d,t] = sum_c x[b,c,t] * w[subj[b],c,d]
// 256(d) x 256(t) tile / block, 8 waves (512 thr), each wave 64(d)x128(t).
// bf16x3 split precision (hi*hi + hi*lo + lo*hi), fp32 MFMA accum.
// LDS row = d (or t), 8 granules x 8 shorts: g0-3 = hi(k), g4-7 = lo.
// Slot swizzle swz(row) = (row ^ row>>3) & 7; lo-offset = hi ^ 32 shorts.
// Round-9 lesson: 2-barrier single-buffer schedule serializes staging
// (cvt ~2100cy + ds_write) against MFMA (3725cy) -> 7875cy/step, MfmaUtil
// = 3725/7875 = 47% exactly as measured. Fix: LDS DOUBLE-BUFFER -- stage
// tile k+1 into buf B while MFMAing tile k from buf A, ONE barrier/step.
// cvt VALU + ds_write(next) overlap ds_read+MFMA(cur): separate pipes/bufs.
// T14 kept: raw global loads for tile k+2 issued at top of step k.
// __launch_bounds__(512,1): 2 waves/SIMD, <=256 regs/wave (round-7 lesson).

#define KSTEP(VCVT, VLD, KLOAD, WRD, XRD, SWRBASE)                              \
  {                                                                             \
    const int ksafe = (KLOAD) & (CDIM - 1); /* tail: dummy wrapped re-read */   \
    _Pragma("unroll")                                                           \
    for (int j = 0; j < 8; ++j)                                                 \
        VLD[j] = *(const float4*)(sp + ((size_t)(ksafe + (cg << 3) + j) << 10)); \
    u32x4 hg[4], lg[4];                                                         \
    _Pragma("unroll")                                                           \
    for (int rr = 0; rr < 4; ++rr) {                                            \
      _Pragma("unroll")                                                         \
      for (int p = 0; p < 4; ++p) {                                             \
        const float f0 = VCVT[2 * p][rr];                                       \
        const float f1 = VCVT[2 * p + 1][rr];                                   \
        const unsigned h = cvt_pk_bf16(f0, f1);                                 \
        const float l0 = f0 - __uint_as_float(h << 16);                         \
        const float l1 = f1 - __uint_as_float(h & 0xFFFF0000u);                 \
        hg[rr][p] = h;                                                          \
        lg[rr][p] = cvt_pk_bf16(l0, l1);                                        \
      }                                                                         \
    }                                                                           \
    _Pragma("unroll")                                                           \
    for (int rr = 0; rr < 4; ++rr) {                                            \
      const int row = col0 + rr;                                                \
      short* sl = (SWRBASE) + row * 64;                                         \
      const int so = ((cg ^ ((row ^ (row >> 3)) & 7)) << 3);                    \
      *(u32x4*)(sl + so) = hg[rr];                                              \
      *(u32x4*)(sl + (so ^ 32)) = lg[rr];                                       \
    }                                                                           \
    bf16x8 ah[4], al[4];                                                        \
    _Pragma("unroll")                                                           \
    for (int m = 0; m < 4; ++m) {                                               \
      const short* wrow = (WRD) + (wdOff + m * 16 + fr) * 64;                   \
      ah[m] = *(const bf16x8*)(wrow + offHW[m]);                                \
      al[m] = *(const bf16x8*)(wrow + (offHW[m] ^ 32));                         \
    }                                                                           \
    _Pragma("unroll")                                                           \
    for (int np = 0; np < 4; ++np) {                                            \
      const int n0 = 2 * np, n1 = 2 * np + 1;                                   \
      const short* xr0 = (XRD) + (wtOff + n0 * 16 + fr) * 64;                   \
      const short* xr1 = (XRD) + (wtOff + n1 * 16 + fr) * 64;                   \
      const bf16x8 bh0 = *(const bf16x8*)(xr0 + offHX[n0]);                     \
      const bf16x8 bl0 = *(const bf16x8*)(xr0 + (offHX[n0] ^ 32));              \
      const bf16x8 bh1 = *(const bf16x8*)(xr1 + offHX[n1]);                     \
      const bf16x8 bl1 = *(const bf16x8*)(xr1 + (offHX[n1] ^ 32));              \
      _Pragma("unroll")                                                         \
      for (int m = 0; m < 4; ++m)                                               \
        acc[m][n0] = __builtin_amdgcn_mfma_f32_16x16x32_bf16(ah[m], bh0, acc[m][n0], 0, 0, 0); \
      _Pragma("unroll")                                                         \
      for (int m = 0; m < 4; ++m)                                               \
        acc[m][n1] = __builtin_amdgcn_mfma_f32_16x16x32_bf16(ah[m], bh1, acc[m][n1], 0, 0, 0); \
      _Pragma("unroll")                                                         \
      for (int m = 0; m < 4; ++m)                                               \
        acc[m][n0] = __builtin_amdgcn_mfma_f32_16x16x32_bf16(ah[m], bl0, acc[m][n0], 0, 0, 0); \
      _Pragma("unroll")                                                         \
      for (int m = 0; m < 4; ++m)                                               \
        acc[m][n1] = __builtin_amdgcn_mfma_f32_16x16x32_bf16(ah[m], bl1, acc[m][n1], 0, 0, 0); \
      _Pragma("unroll")                                                         \
      for (int m = 0; m < 4; ++m)                                               \
        acc[m][n0] = __builtin_amdgcn_mfma_f32_16x16x32_bf16(al[m], bh0, acc[m][n0], 0, 0, 0); \
      _Pragma("unroll")                                                         \
      for (int m = 0; m < 4; ++m)                                               \
        acc[m][n1] = __builtin_amdgcn_mfma_f32_16x16x32_bf16(al[m], bh1, acc[m][n1], 0, 0, 0); \
    }                                                                           \
    __syncthreads();                                                            \
  }

__global__ __launch_bounds__(512, 1)
void subject_gemm(const float* __restrict__ x, const int* __restrict__ subj,
                  const float* __restrict__ w, float* __restrict__ out)
{
    __shared__ short WtA[256 * 64], XtA[256 * 64];   // buffer A: 64 KB
    __shared__ short WtB[256 * 64], XtB[256 * 64];   // buffer B: 64 KB

    // XCD mapping: 1024 blocks; bid&7 = XCD; 8 whole batches per XCD;
    // ttile fastest so consecutive slots share the W panel in L2.
    const int bid = blockIdx.x;
    const int xcd = bid & 7;
    const int slot = bid >> 3;               // 0..127 per XCD
    const int b = (xcd << 3) | (slot >> 4);  // 8 batches per XCD
    const int r = slot & 15;
    const int dtile = (r >> 2) << 8;
    const int ttile = (r & 3) << 8;

    const int s = subj[b];
    const float* __restrict__ wB = w + (size_t)s * (CDIM * DDIM);
    const float* __restrict__ xB = x + (size_t)b * (CDIM * TDIM);

    const int tid = threadIdx.x;
    const int lane = tid & 63;
    const int wave = tid >> 6;               // 0..7

    // ---- staging role: threads 0-255 stage W, 256-511 stage X ----
    const int ht = tid & 255;
    const int tq = ht & 63;            // column-quad 0..63 -> 256 cols
    const int cg = ht >> 6;            // k-granule 0..3 (8 c's each)
    const int col0 = tq << 2;
    const bool isW = (tid < 256);
    const float* sp = (isW ? wB + dtile : xB + ttile) + col0;
    short* sldsA = (isW ? WtA : XtA);
    short* sldsB = (isW ? WtB : XtB);

    // ---- fragment assignment: wave tile 64(d) x 128(t) ----
    const int wdOff = (wave >> 1) << 6;  // 0/64/128/192
    const int wtOff = (wave & 1) << 7;   // 0/128
    const int fr = lane & 15;
    const int fg = lane >> 4;

    int offHW[4], offHX[8];
    #pragma unroll
    for (int m = 0; m < 4; ++m) {
        const int rowW = wdOff + m * 16 + fr;
        offHW[m] = ((fg ^ ((rowW ^ (rowW >> 3)) & 7)) << 3);
    }
    #pragma unroll
    for (int n = 0; n < 8; ++n) {
        const int rowX = wtOff + n * 16 + fr;
        offHX[n] = ((fg ^ ((rowX ^ (rowX >> 3)) & 7)) << 3);
    }

    f32x4 acc[4][8] = {};

    // ---- prologue: tile0 -> buf A; tile1 raw -> vb ----
    float4 va[8], vb[8];
    #pragma unroll
    for (int j = 0; j < 8; ++j)
        va[j] = *(const float4*)(sp + ((size_t)((cg << 3) + j) << 10));
    {
        u32x4 hg[4], lg[4];
        #pragma unroll
        for (int rr = 0; rr < 4; ++rr) {
            #pragma unroll
            for (int p = 0; p < 4; ++p) {
                const float f0 = va[2 * p][rr];
                const float f1 = va[2 * p + 1][rr];
                const unsigned h = cvt_pk_bf16(f0, f1);
                const float l0 = f0 - __uint_as_float(h << 16);
                const float l1 = f1 - __uint_as_float(h & 0xFFFF0000u);
                hg[rr][p] = h;
                lg[rr][p] = cvt_pk_bf16(l0, l1);
            }
        }
        #pragma unroll
        for (int rr = 0; rr < 4; ++rr) {
            const int row = col0 + rr;
            short* sl = sldsA + row * 64;
            const int so = ((cg ^ ((row ^ (row >> 3)) & 7)) << 3);
            *(u32x4*)(sl + so) = hg[rr];
            *(u32x4*)(sl + (so ^ 32)) = lg[rr];
        }
    }
    #pragma unroll
    for (int j = 0; j < 8; ++j)
        vb[j] = *(const float4*)(sp + ((size_t)(BK + (cg << 3) + j) << 10));
    __syncthreads();

    // ---- main loop: compute cur-buf, stage next-buf, load next-next ----
    for (int k0 = 0; k0 < CDIM; k0 += 2 * BK) {
        KSTEP(vb, va, k0 + 2 * BK, WtA, XtA, sldsB);   // compute tile k0 (A)
        KSTEP(va, vb, k0 + 3 * BK, WtB, XtB, sldsA);   // compute tile k0+BK (B)
    }

    // epilogue: C/D col = lane&15 (t), row = (lane>>4)*4 + q (d)
    float* __restrict__ oB = out + (size_t)b * (DDIM * TDIM)
                           + (size_t)(dtile + wdOff) * TDIM + (ttile + wtOff);
    #pragma unroll
    for (int m = 0; m < 4; ++m) {
        #pragma unroll
        for (int q = 0; q < 4; ++q) {
            const int d = m * 16 + (fg << 2) + q;
            float* orow = oB + (size_t)d * TDIM;
            #pragma unroll
            for (int n = 0; n < 8; ++n) {
                orow[n * 16 + fr] = acc[m][n][q];
            }
        }
    }
}

extern "C" void kernel_launch(void* const* d_in, const int* in_sizes, int n_in,
                              void* d_out, int out_size, void* d_ws, size_t ws_size,
                              hipStream_t stream) {
    const float* x = (const float*)d_in[0];
    const int* subjects = (const int*)d_in[1];
    const float* w = (const float*)d_in[2];
    float* out = (float*)d_out;
    subject_gemm<<<dim3(1024), dim3(512), 0, stream>>>(x, subjects, w, out);
}

// Round 11
// 485.945 us; speedup vs baseline: 1.8101x; 1.8101x over previous
//
#include <hip/hip_runtime.h>
#include <hip/hip_bf16.h>

typedef __attribute__((ext_vector_type(8))) short bf16x8;
typedef __attribute__((ext_vector_type(4))) float f32x4;
typedef __attribute__((ext_vector_type(4))) unsigned u32x4;

#define CDIM 1024
#define DDIM 1024
#define TDIM 1024
#define BK 32

__device__ __forceinline__ unsigned cvt_pk_bf16(float a, float b) {
    unsigned r;
    asm("v_cvt_pk_bf16_f32 %0, %1, %2" : "=v"(r) : "v"(a), "v"(b));
    return r;
}

// out[b,d,t] = sum_c x[b,c,t] * w[subj[b],c,d]
// 256x256 tile / block, 8 waves (512 thr), each wave 64(d)x128(t).
// bf16x3 split precision (hi*hi + hi*lo + lo*hi), fp32 MFMA accum.
// LDS row = d (or t), 8 granules x 8 shorts: g0-3 = hi, g4-7 = lo;
// slot swizzle (row ^ row>>3)&7, lo = hi ^ 32 shorts.
// LDS double-buffer, ONE barrier/step: step k = {issue loads tile k+1 |
// MFMA tile k from buf-cur | cvt+ds_write tile k+1 to buf-next | barrier}.
// Round-10 lesson: TWO reg tile buffers (va+vb) + merged body spilled
// (FETCH 275->841 MB = scratch traffic, 18% MfmaUtil). This version keeps
// ONE v[8] buffer + per-rr convert-write (hg/lg live 8 regs not 32);
// sched_barrier(0) pins the 3-phase order so cvt's vmcnt wait stays
// below the MFMA section. __launch_bounds__(512,1): 256 regs/wave cap.

#define KSTEP(KLOAD, WRD, XRD, SWRBASE)                                         \
  {                                                                             \
    const int ksafe = (KLOAD) & (CDIM - 1); /* tail: dummy wrapped re-read */   \
    float4 v[8];                                                                \
    _Pragma("unroll")                                                           \
    for (int j = 0; j < 8; ++j)                                                 \
        v[j] = *(const float4*)(sp + ((size_t)(ksafe + (cg << 3) + j) << 10));  \
    __builtin_amdgcn_sched_barrier(0);                                          \
    bf16x8 ah[4], al[4];                                                        \
    _Pragma("unroll")                                                           \
    for (int m = 0; m < 4; ++m) {                                               \
      const short* wrow = (WRD) + (wdOff + m * 16 + fr) * 64;                   \
      ah[m] = *(const bf16x8*)(wrow + offHW[m]);                                \
      al[m] = *(const bf16x8*)(wrow + (offHW[m] ^ 32));                         \
    }                                                                           \
    _Pragma("unroll")                                                           \
    for (int np = 0; np < 4; ++np) {                                            \
      const int n0 = 2 * np, n1 = 2 * np + 1;                                   \
      const short* xr0 = (XRD) + (wtOff + n0 * 16 + fr) * 64;                   \
      const short* xr1 = (XRD) + (wtOff + n1 * 16 + fr) * 64;                   \
      const bf16x8 bh0 = *(const bf16x8*)(xr0 + offHX[n0]);                     \
      const bf16x8 bl0 = *(const bf16x8*)(xr0 + (offHX[n0] ^ 32));              \
      const bf16x8 bh1 = *(const bf16x8*)(xr1 + offHX[n1]);                     \
      const bf16x8 bl1 = *(const bf16x8*)(xr1 + (offHX[n1] ^ 32));              \
      _Pragma("unroll")                                                         \
      for (int m = 0; m < 4; ++m)                                               \
        acc[m][n0] = __builtin_amdgcn_mfma_f32_16x16x32_bf16(ah[m], bh0, acc[m][n0], 0, 0, 0); \
      _Pragma("unroll")                                                         \
      for (int m = 0; m < 4; ++m)                                               \
        acc[m][n1] = __builtin_amdgcn_mfma_f32_16x16x32_bf16(ah[m], bh1, acc[m][n1], 0, 0, 0); \
      _Pragma("unroll")                                                         \
      for (int m = 0; m < 4; ++m)                                               \
        acc[m][n0] = __builtin_amdgcn_mfma_f32_16x16x32_bf16(ah[m], bl0, acc[m][n0], 0, 0, 0); \
      _Pragma("unroll")                                                         \
      for (int m = 0; m < 4; ++m)                                               \
        acc[m][n1] = __builtin_amdgcn_mfma_f32_16x16x32_bf16(ah[m], bl1, acc[m][n1], 0, 0, 0); \
      _Pragma("unroll")                                                         \
      for (int m = 0; m < 4; ++m)                                               \
        acc[m][n0] = __builtin_amdgcn_mfma_f32_16x16x32_bf16(al[m], bh0, acc[m][n0], 0, 0, 0); \
      _Pragma("unroll")                                                         \
      for (int m = 0; m < 4; ++m)                                               \
        acc[m][n1] = __builtin_amdgcn_mfma_f32_16x16x32_bf16(al[m], bh1, acc[m][n1], 0, 0, 0); \
    }                                                                           \
    __builtin_amdgcn_sched_barrier(0);                                          \
    _Pragma("unroll")                                                           \
    for (int rr = 0; rr < 4; ++rr) {                                            \
      u32x4 hg, lg;                                                             \
      _Pragma("unroll")                                                         \
      for (int p = 0; p < 4; ++p) {                                             \
        const float f0 = v[2 * p][rr];                                          \
        const float f1 = v[2 * p + 1][rr];                                      \
        const unsigned h = cvt_pk_bf16(f0, f1);                                 \
        const float l0 = f0 - __uint_as_float(h << 16);                         \
        const float l1 = f1 - __uint_as_float(h & 0xFFFF0000u);                 \
        hg[p] = h;                                                              \
        lg[p] = cvt_pk_bf16(l0, l1);                                            \
      }                                                                         \
      const int row = col0 + rr;                                                \
      short* sl = (SWRBASE) + row * 64;                                         \
      const int so = ((cg ^ ((row ^ (row >> 3)) & 7)) << 3);                    \
      *(u32x4*)(sl + so) = hg;                                                  \
      *(u32x4*)(sl + (so ^ 32)) = lg;                                           \
    }                                                                           \
    __syncthreads();                                                            \
  }

__global__ __launch_bounds__(512, 1)
void subject_gemm(const float* __restrict__ x, const int* __restrict__ subj,
                  const float* __restrict__ w, float* __restrict__ out)
{
    __shared__ short WtA[256 * 64], XtA[256 * 64];   // buffer A: 64 KB
    __shared__ short WtB[256 * 64], XtB[256 * 64];   // buffer B: 64 KB

    // XCD mapping: 1024 blocks; bid&7 = XCD; 8 whole batches per XCD;
    // ttile fastest so consecutive slots share the W panel in L2.
    const int bid = blockIdx.x;
    const int xcd = bid & 7;
    const int slot = bid >> 3;               // 0..127 per XCD
    const int b = (xcd << 3) | (slot >> 4);  // 8 batches per XCD
    const int r = slot & 15;
    const int dtile = (r >> 2) << 8;
    const int ttile = (r & 3) << 8;

    const int s = subj[b];
    const float* __restrict__ wB = w + (size_t)s * (CDIM * DDIM);
    const float* __restrict__ xB = x + (size_t)b * (CDIM * TDIM);

    const int tid = threadIdx.x;
    const int lane = tid & 63;
    const int wave = tid >> 6;               // 0..7

    // ---- staging role: threads 0-255 stage W, 256-511 stage X ----
    const int ht = tid & 255;
    const int tq = ht & 63;            // column-quad 0..63 -> 256 cols
    const int cg = ht >> 6;            // k-granule 0..3 (8 c's each)
    const int col0 = tq << 2;
    const bool isW = (tid < 256);
    const float* sp = (isW ? wB + dtile : xB + ttile) + col0;
    short* sldsA = (isW ? WtA : XtA);
    short* sldsB = (isW ? WtB : XtB);

    // ---- fragment assignment: wave tile 64(d) x 128(t) ----
    const int wdOff = (wave >> 1) << 6;  // 0/64/128/192
    const int wtOff = (wave & 1) << 7;   // 0/128
    const int fr = lane & 15;
    const int fg = lane >> 4;

    int offHW[4], offHX[8];
    #pragma unroll
    for (int m = 0; m < 4; ++m) {
        const int rowW = wdOff + m * 16 + fr;
        offHW[m] = ((fg ^ ((rowW ^ (rowW >> 3)) & 7)) << 3);
    }
    #pragma unroll
    for (int n = 0; n < 8; ++n) {
        const int rowX = wtOff + n * 16 + fr;
        offHX[n] = ((fg ^ ((rowX ^ (rowX >> 3)) & 7)) << 3);
    }

    f32x4 acc[4][8] = {};

    // ---- prologue: stage tile 0 into buffer A ----
    {
        float4 v[8];
        #pragma unroll
        for (int j = 0; j < 8; ++j)
            v[j] = *(const float4*)(sp + ((size_t)((cg << 3) + j) << 10));
        #pragma unroll
        for (int rr = 0; rr < 4; ++rr) {
            u32x4 hg, lg;
            #pragma unroll
            for (int p = 0; p < 4; ++p) {
                const float f0 = v[2 * p][rr];
                const float f1 = v[2 * p + 1][rr];
                const unsigned h = cvt_pk_bf16(f0, f1);
                const float l0 = f0 - __uint_as_float(h << 16);
                const float l1 = f1 - __uint_as_float(h & 0xFFFF0000u);
                hg[p] = h;
                lg[p] = cvt_pk_bf16(l0, l1);
            }
            const int row = col0 + rr;
            short* sl = sldsA + row * 64;
            const int so = ((cg ^ ((row ^ (row >> 3)) & 7)) << 3);
            *(u32x4*)(sl + so) = hg;
            *(u32x4*)(sl + (so ^ 32)) = lg;
        }
        __syncthreads();
    }

    // ---- main loop: one barrier per K-step ----
    for (int k0 = 0; k0 < CDIM; k0 += 2 * BK) {
        KSTEP(k0 + BK,     WtA, XtA, sldsB);   // compute tile k0 (A), stage k0+BK -> B
        KSTEP(k0 + 2 * BK, WtB, XtB, sldsA);   // compute tile k0+BK (B), stage -> A
    }

    // epilogue: C/D col = lane&15 (t), row = (lane>>4)*4 + q (d)
    float* __restrict__ oB = out + (size_t)b * (DDIM * TDIM)
                           + (size_t)(dtile + wdOff) * TDIM + (ttile + wtOff);
    #pragma unroll
    for (int m = 0; m < 4; ++m) {
        #pragma unroll
        for (int q = 0; q < 4; ++q) {
            const int d = m * 16 + (fg << 2) + q;
            float* orow = oB + (size_t)d * TDIM;
            #pragma unroll
            for (int n = 0; n < 8; ++n) {
                orow[n * 16 + fr] = acc[m][n][q];
            }
        }
    }
}

extern "C" void kernel_launch(void* const* d_in, const int* in_sizes, int n_in,
                              void* d_out, int out_size, void* d_ws, size_t ws_size,
                              hipStream_t stream) {
    const float* x = (const float*)d_in[0];
    const int* subjects = (const int*)d_in[1];
    const float* w = (const float*)d_in[2];
    float* out = (float*)d_out;
    subject_gemm<<<dim3(1024), dim3(512), 0, stream>>>(x, subjects, w, out);
}

// Round 12
// 467.140 us; speedup vs baseline: 1.8830x; 1.0403x over previous
//
#include <hip/hip_runtime.h>
#include <hip/hip_bf16.h>

typedef __attribute__((ext_vector_type(8))) short bf16x8;
typedef __attribute__((ext_vector_type(4))) float f32x4;
typedef __attribute__((ext_vector_type(4))) unsigned u32x4;

#define CDIM 1024
#define DDIM 1024
#define TDIM 1024
#define BK 32

__device__ __forceinline__ unsigned cvt_pk_bf16(float a, float b) {
    unsigned r;
    asm("v_cvt_pk_bf16_f32 %0, %1, %2" : "=v"(r) : "v"(a), "v"(b));
    return r;
}

// out[b,d,t] = sum_c x[b,c,t] * w[subj[b],c,d]
// 256x256 tile / block, 8 waves (512 thr), each wave 64(d)x128(t).
// bf16x3 split precision (hi*hi + hi*lo + lo*hi), fp32 MFMA accum.
// LDS row = d (or t), 8 granules x 8 shorts: g0-3 = hi, g4-7 = lo;
// slot swizzle (row ^ row>>3)&7, lo = hi ^ 32 shorts.
// LDS double-buffer, ONE barrier per K-step. Step k:
//   loads tile k+1 -> v[8]; then 4 PHASES, each:
//   {ds_read B-frags pair p | 24 MFMA (tile k, buf-cur) | cvt row p of v +
//    2 ds_write to buf-NEXT}  -- no intra-step barrier needed (write/read
//   go to different buffers), NO sched_barrier pins.
// Round-11 lesson: sched_barrier(0) pins forbade cvt/ds_write from hiding
// in the MFMA shadow -> phase fully exposed (MfmaUtil 34%). This version
// lets the scheduler co-issue VALU cvt + ds_write under MFMA (sep. pipes).
// Round-10 lesson: one v[8] only (two reg tile buffers spilled).
// Round-7 lesson: __launch_bounds__(512,1) -> 256 unified regs/wave.

#define KSTEP(KLOAD, WRD, XRD, SWRBASE)                                         \
  {                                                                             \
    const int ksafe = (KLOAD) & (CDIM - 1); /* tail: dummy wrapped re-read */   \
    float4 v[8];                                                                \
    _Pragma("unroll")                                                           \
    for (int j = 0; j < 8; ++j)                                                 \
        v[j] = *(const float4*)(sp + ((size_t)(ksafe + (cg << 3) + j) << 10));  \
    bf16x8 ah[4], al[4];                                                        \
    _Pragma("unroll")                                                           \
    for (int m = 0; m < 4; ++m) {                                               \
      const short* wrow = (WRD) + (wdOff + m * 16 + fr) * 64;                   \
      ah[m] = *(const bf16x8*)(wrow + offHW[m]);                                \
      al[m] = *(const bf16x8*)(wrow + (offHW[m] ^ 32));                         \
    }                                                                           \
    _Pragma("unroll")                                                           \
    for (int ph = 0; ph < 4; ++ph) {                                            \
      const int n0 = 2 * ph, n1 = 2 * ph + 1;                                   \
      const short* xr0 = (XRD) + (wtOff + n0 * 16 + fr) * 64;                   \
      const short* xr1 = (XRD) + (wtOff + n1 * 16 + fr) * 64;                   \
      const bf16x8 bh0 = *(const bf16x8*)(xr0 + offHX[n0]);                     \
      const bf16x8 bl0 = *(const bf16x8*)(xr0 + (offHX[n0] ^ 32));              \
      const bf16x8 bh1 = *(const bf16x8*)(xr1 + offHX[n1]);                     \
      const bf16x8 bl1 = *(const bf16x8*)(xr1 + (offHX[n1] ^ 32));              \
      _Pragma("unroll")                                                         \
      for (int m = 0; m < 4; ++m)                                               \
        acc[m][n0] = __builtin_amdgcn_mfma_f32_16x16x32_bf16(ah[m], bh0, acc[m][n0], 0, 0, 0); \
      _Pragma("unroll")                                                         \
      for (int m = 0; m < 4; ++m)                                               \
        acc[m][n1] = __builtin_amdgcn_mfma_f32_16x16x32_bf16(ah[m], bh1, acc[m][n1], 0, 0, 0); \
      _Pragma("unroll")                                                         \
      for (int m = 0; m < 4; ++m)                                               \
        acc[m][n0] = __builtin_amdgcn_mfma_f32_16x16x32_bf16(ah[m], bl0, acc[m][n0], 0, 0, 0); \
      _Pragma("unroll")                                                         \
      for (int m = 0; m < 4; ++m)                                               \
        acc[m][n1] = __builtin_amdgcn_mfma_f32_16x16x32_bf16(ah[m], bl1, acc[m][n1], 0, 0, 0); \
      _Pragma("unroll")                                                         \
      for (int m = 0; m < 4; ++m)                                               \
        acc[m][n0] = __builtin_amdgcn_mfma_f32_16x16x32_bf16(al[m], bh0, acc[m][n0], 0, 0, 0); \
      _Pragma("unroll")                                                         \
      for (int m = 0; m < 4; ++m)                                               \
        acc[m][n1] = __builtin_amdgcn_mfma_f32_16x16x32_bf16(al[m], bh1, acc[m][n1], 0, 0, 0); \
      /* staging slice for this phase: cvt row ph of v, write to buf-next */    \
      {                                                                         \
        u32x4 hg, lg;                                                           \
        _Pragma("unroll")                                                       \
        for (int p = 0; p < 4; ++p) {                                           \
          const float f0 = v[2 * p][ph];                                        \
          const float f1 = v[2 * p + 1][ph];                                    \
          const unsigned h = cvt_pk_bf16(f0, f1);                               \
          const float l0 = f0 - __uint_as_float(h << 16);                       \
          const float l1 = f1 - __uint_as_float(h & 0xFFFF0000u);               \
          hg[p] = h;                                                            \
          lg[p] = cvt_pk_bf16(l0, l1);                                          \
        }                                                                       \
        const int row = col0 + ph;                                              \
        short* sl = (SWRBASE) + row * 64;                                       \
        const int so = ((cg ^ ((row ^ (row >> 3)) & 7)) << 3);                  \
        *(u32x4*)(sl + so) = hg;                                                \
        *(u32x4*)(sl + (so ^ 32)) = lg;                                         \
      }                                                                         \
    }                                                                           \
    __syncthreads();                                                            \
  }

__global__ __launch_bounds__(512, 1)
void subject_gemm(const float* __restrict__ x, const int* __restrict__ subj,
                  const float* __restrict__ w, float* __restrict__ out)
{
    __shared__ short WtA[256 * 64], XtA[256 * 64];   // buffer A: 64 KB
    __shared__ short WtB[256 * 64], XtB[256 * 64];   // buffer B: 64 KB

    // XCD mapping: 1024 blocks; bid&7 = XCD; 8 whole batches per XCD;
    // ttile fastest so consecutive slots share the W panel in L2.
    const int bid = blockIdx.x;
    const int xcd = bid & 7;
    const int slot = bid >> 3;               // 0..127 per XCD
    const int b = (xcd << 3) | (slot >> 4);  // 8 batches per XCD
    const int r = slot & 15;
    const int dtile = (r >> 2) << 8;
    const int ttile = (r & 3) << 8;

    const int s = subj[b];
    const float* __restrict__ wB = w + (size_t)s * (CDIM * DDIM);
    const float* __restrict__ xB = x + (size_t)b * (CDIM * TDIM);

    const int tid = threadIdx.x;
    const int lane = tid & 63;
    const int wave = tid >> 6;               // 0..7

    // ---- staging role: threads 0-255 stage W, 256-511 stage X ----
    const int ht = tid & 255;
    const int tq = ht & 63;            // column-quad 0..63 -> 256 cols
    const int cg = ht >> 6;            // k-granule 0..3 (8 c's each)
    const int col0 = tq << 2;
    const bool isW = (tid < 256);
    const float* sp = (isW ? wB + dtile : xB + ttile) + col0;
    short* sldsA = (isW ? WtA : XtA);
    short* sldsB = (isW ? WtB : XtB);

    // ---- fragment assignment: wave tile 64(d) x 128(t) ----
    const int wdOff = (wave >> 1) << 6;  // 0/64/128/192
    const int wtOff = (wave & 1) << 7;   // 0/128
    const int fr = lane & 15;
    const int fg = lane >> 4;

    int offHW[4], offHX[8];
    #pragma unroll
    for (int m = 0; m < 4; ++m) {
        const int rowW = wdOff + m * 16 + fr;
        offHW[m] = ((fg ^ ((rowW ^ (rowW >> 3)) & 7)) << 3);
    }
    #pragma unroll
    for (int n = 0; n < 8; ++n) {
        const int rowX = wtOff + n * 16 + fr;
        offHX[n] = ((fg ^ ((rowX ^ (rowX >> 3)) & 7)) << 3);
    }

    f32x4 acc[4][8] = {};

    // ---- prologue: stage tile 0 into buffer A ----
    {
        float4 v[8];
        #pragma unroll
        for (int j = 0; j < 8; ++j)
            v[j] = *(const float4*)(sp + ((size_t)((cg << 3) + j) << 10));
        #pragma unroll
        for (int rr = 0; rr < 4; ++rr) {
            u32x4 hg, lg;
            #pragma unroll
            for (int p = 0; p < 4; ++p) {
                const float f0 = v[2 * p][rr];
                const float f1 = v[2 * p + 1][rr];
                const unsigned h = cvt_pk_bf16(f0, f1);
                const float l0 = f0 - __uint_as_float(h << 16);
                const float l1 = f1 - __uint_as_float(h & 0xFFFF0000u);
                hg[p] = h;
                lg[p] = cvt_pk_bf16(l0, l1);
            }
            const int row = col0 + rr;
            short* sl = sldsA + row * 64;
            const int so = ((cg ^ ((row ^ (row >> 3)) & 7)) << 3);
            *(u32x4*)(sl + so) = hg;
            *(u32x4*)(sl + (so ^ 32)) = lg;
        }
        __syncthreads();
    }

    // ---- main loop: one barrier per K-step ----
    for (int k0 = 0; k0 < CDIM; k0 += 2 * BK) {
        KSTEP(k0 + BK,     WtA, XtA, sldsB);   // compute tile k0 (A), stage k0+BK -> B
        KSTEP(k0 + 2 * BK, WtB, XtB, sldsA);   // compute tile k0+BK (B), stage -> A
    }

    // epilogue: C/D col = lane&15 (t), row = (lane>>4)*4 + q (d)
    float* __restrict__ oB = out + (size_t)b * (DDIM * TDIM)
                           + (size_t)(dtile + wdOff) * TDIM + (ttile + wtOff);
    #pragma unroll
    for (int m = 0; m < 4; ++m) {
        #pragma unroll
        for (int q = 0; q < 4; ++q) {
            const int d = m * 16 + (fg << 2) + q;
            float* orow = oB + (size_t)d * TDIM;
            #pragma unroll
            for (int n = 0; n < 8; ++n) {
                orow[n * 16 + fr] = acc[m][n][q];
            }
        }
    }
}

extern "C" void kernel_launch(void* const* d_in, const int* in_sizes, int n_in,
                              void* d_out, int out_size, void* d_ws, size_t ws_size,
                              hipStream_t stream) {
    const float* x = (const float*)d_in[0];
    const int* subjects = (const int*)d_in[1];
    const float* w = (const float*)d_in[2];
    float* out = (float*)d_out;
    subject_gemm<<<dim3(1024), dim3(512), 0, stream>>>(x, subjects, w, out);
}

// Round 13
// 394.337 us; speedup vs baseline: 2.2306x; 1.1846x over previous
//
#include <hip/hip_runtime.h>
#include <hip/hip_bf16.h>

typedef __attribute__((ext_vector_type(8))) short bf16x8;
typedef __attribute__((ext_vector_type(4))) float f32x4;
typedef __attribute__((ext_vector_type(4))) unsigned u32x4;

#define CDIM 1024
#define DDIM 1024
#define TDIM 1024
#define BK 32

__device__ __forceinline__ unsigned cvt_pk_bf16(float a, float b) {
    unsigned r;
    asm("v_cvt_pk_bf16_f32 %0, %1, %2" : "=v"(r) : "v"(a), "v"(b));
    return r;
}

// out[b,d,t] = sum_c x[b,c,t] * w[subj[b],c,d]
// 256x256 tile / block, 8 waves (512 thr), each wave 64(d)x128(t).
// bf16x3 split precision (hi*hi + hi*lo + lo*hi), fp32 MFMA accum.
// LDS row = d (or t), 8 granules x 8 shorts: g0-3 = hi, g4-7 = lo;
// slot swizzle (row ^ row>>3)&7, lo = hi ^ 32 shorts.
// LDS double-buffer, ONE barrier/step, body order chosen for r9's
// live-range profile (r10-r12 lesson: any layout where v[8] stays live
// through the MFMA cluster spills -> WRITE_SIZE 338 vs 276 MB):
//   body(t): [cvt v(tile t+1) + ds_write -> buf-next]   (v DIES here)
//            [frag-read buf-cur + 96 MFMA (tile t)]     (ah/al/b transient)
//            [issue global loads tile t+2 -> v]         (live across barrier
//            __syncthreads()                             only, not MFMA)
// Writes go to buf-next while MFMAs read buf-cur -> no intra-body ordering;
// scheduler + inter-wave drift overlap cvt/ds_write under MFMA.
// No sched_barrier pins (r11 lesson). __launch_bounds__(512,1) (r7 lesson).

#define KSTEP(KLOAD, WRD, XRD, SWRBASE)                                         \
  {                                                                             \
    /* phase 1: cvt v (raw tile staged last body) -> ds_write buf-next */       \
    _Pragma("unroll")                                                           \
    for (int rr = 0; rr < 4; ++rr) {                                            \
      u32x4 hg, lg;                                                             \
      _Pragma("unroll")                                                         \
      for (int p = 0; p < 4; ++p) {                                             \
        const float f0 = v[2 * p][rr];                                          \
        const float f1 = v[2 * p + 1][rr];                                      \
        const unsigned h = cvt_pk_bf16(f0, f1);                                 \
        const float l0 = f0 - __uint_as_float(h << 16);                         \
        const float l1 = f1 - __uint_as_float(h & 0xFFFF0000u);                 \
        hg[p] = h;                                                              \
        lg[p] = cvt_pk_bf16(l0, l1);                                            \
      }                                                                         \
      const int row = col0 + rr;                                                \
      short* sl = (SWRBASE) + row * 64;                                         \
      const int so = ((cg ^ ((row ^ (row >> 3)) & 7)) << 3);                    \
      *(u32x4*)(sl + so) = hg;                                                  \
      *(u32x4*)(sl + (so ^ 32)) = lg;                                           \
    }                                                                           \
    /* phase 2: fragment reads + MFMA from buf-cur */                           \
    {                                                                           \
      bf16x8 ah[4], al[4];                                                      \
      _Pragma("unroll")                                                         \
      for (int m = 0; m < 4; ++m) {                                             \
        const short* wrow = (WRD) + (wdOff + m * 16 + fr) * 64;                 \
        ah[m] = *(const bf16x8*)(wrow + offHW[m]);                              \
        al[m] = *(const bf16x8*)(wrow + (offHW[m] ^ 32));                       \
      }                                                                         \
      _Pragma("unroll")                                                         \
      for (int np = 0; np < 4; ++np) {                                          \
        const int n0 = 2 * np, n1 = 2 * np + 1;                                 \
        const short* xr0 = (XRD) + (wtOff + n0 * 16 + fr) * 64;                 \
        const short* xr1 = (XRD) + (wtOff + n1 * 16 + fr) * 64;                 \
        const bf16x8 bh0 = *(const bf16x8*)(xr0 + offHX[n0]);                   \
        const bf16x8 bl0 = *(const bf16x8*)(xr0 + (offHX[n0] ^ 32));            \
        const bf16x8 bh1 = *(const bf16x8*)(xr1 + offHX[n1]);                   \
        const bf16x8 bl1 = *(const bf16x8*)(xr1 + (offHX[n1] ^ 32));            \
        _Pragma("unroll")                                                       \
        for (int m = 0; m < 4; ++m)                                             \
          acc[m][n0] = __builtin_amdgcn_mfma_f32_16x16x32_bf16(ah[m], bh0, acc[m][n0], 0, 0, 0); \
        _Pragma("unroll")                                                       \
        for (int m = 0; m < 4; ++m)                                             \
          acc[m][n1] = __builtin_amdgcn_mfma_f32_16x16x32_bf16(ah[m], bh1, acc[m][n1], 0, 0, 0); \
        _Pragma("unroll")                                                       \
        for (int m = 0; m < 4; ++m)                                             \
          acc[m][n0] = __builtin_amdgcn_mfma_f32_16x16x32_bf16(ah[m], bl0, acc[m][n0], 0, 0, 0); \
        _Pragma("unroll")                                                       \
        for (int m = 0; m < 4; ++m)                                             \
          acc[m][n1] = __builtin_amdgcn_mfma_f32_16x16x32_bf16(ah[m], bl1, acc[m][n1], 0, 0, 0); \
        _Pragma("unroll")                                                       \
        for (int m = 0; m < 4; ++m)                                             \
          acc[m][n0] = __builtin_amdgcn_mfma_f32_16x16x32_bf16(al[m], bh0, acc[m][n0], 0, 0, 0); \
        _Pragma("unroll")                                                       \
        for (int m = 0; m < 4; ++m)                                             \
          acc[m][n1] = __builtin_amdgcn_mfma_f32_16x16x32_bf16(al[m], bh1, acc[m][n1], 0, 0, 0); \
      }                                                                         \
    }                                                                           \
    /* phase 3: issue raw loads for tile t+2 -> v (live across barrier) */      \
    {                                                                           \
      const int ksafe = (KLOAD) & (CDIM - 1); /* tail: dummy wrapped re-read */ \
      _Pragma("unroll")                                                         \
      for (int j = 0; j < 8; ++j)                                               \
        v[j] = *(const float4*)(sp + ((size_t)(ksafe + (cg << 3) + j) << 10));  \
    }                                                                           \
    __syncthreads();                                                            \
  }

__global__ __launch_bounds__(512, 1)
void subject_gemm(const float* __restrict__ x, const int* __restrict__ subj,
                  const float* __restrict__ w, float* __restrict__ out)
{
    __shared__ short WtA[256 * 64], XtA[256 * 64];   // buffer A: 64 KB
    __shared__ short WtB[256 * 64], XtB[256 * 64];   // buffer B: 64 KB

    // XCD mapping: 1024 blocks; bid&7 = XCD; 8 whole batches per XCD;
    // ttile fastest so consecutive slots share the W panel in L2.
    const int bid = blockIdx.x;
    const int xcd = bid & 7;
    const int slot = bid >> 3;               // 0..127 per XCD
    const int b = (xcd << 3) | (slot >> 4);  // 8 batches per XCD
    const int r = slot & 15;
    const int dtile = (r >> 2) << 8;
    const int ttile = (r & 3) << 8;

    const int s = subj[b];
    const float* __restrict__ wB = w + (size_t)s * (CDIM * DDIM);
    const float* __restrict__ xB = x + (size_t)b * (CDIM * TDIM);

    const int tid = threadIdx.x;
    const int lane = tid & 63;
    const int wave = tid >> 6;               // 0..7

    // ---- staging role: threads 0-255 stage W, 256-511 stage X ----
    const int ht = tid & 255;
    const int tq = ht & 63;            // column-quad 0..63 -> 256 cols
    const int cg = ht >> 6;            // k-granule 0..3 (8 c's each)
    const int col0 = tq << 2;
    const bool isW = (tid < 256);
    const float* sp = (isW ? wB + dtile : xB + ttile) + col0;
    short* sldsA = (isW ? WtA : XtA);
    short* sldsB = (isW ? WtB : XtB);

    // ---- fragment assignment: wave tile 64(d) x 128(t) ----
    const int wdOff = (wave >> 1) << 6;  // 0/64/128/192
    const int wtOff = (wave & 1) << 7;   // 0/128
    const int fr = lane & 15;
    const int fg = lane >> 4;

    int offHW[4], offHX[8];
    #pragma unroll
    for (int m = 0; m < 4; ++m) {
        const int rowW = wdOff + m * 16 + fr;
        offHW[m] = ((fg ^ ((rowW ^ (rowW >> 3)) & 7)) << 3);
    }
    #pragma unroll
    for (int n = 0; n < 8; ++n) {
        const int rowX = wtOff + n * 16 + fr;
        offHX[n] = ((fg ^ ((rowX ^ (rowX >> 3)) & 7)) << 3);
    }

    f32x4 acc[4][8] = {};
    float4 v[8];   // raw-tile register buffer; live only across barriers

    // ---- prologue: stage tile 0 into buffer A; preload tile 1 -> v ----
    #pragma unroll
    for (int j = 0; j < 8; ++j)
        v[j] = *(const float4*)(sp + ((size_t)((cg << 3) + j) << 10));
    #pragma unroll
    for (int rr = 0; rr < 4; ++rr) {
        u32x4 hg, lg;
        #pragma unroll
        for (int p = 0; p < 4; ++p) {
            const float f0 = v[2 * p][rr];
            const float f1 = v[2 * p + 1][rr];
            const unsigned h = cvt_pk_bf16(f0, f1);
            const float l0 = f0 - __uint_as_float(h << 16);
            const float l1 = f1 - __uint_as_float(h & 0xFFFF0000u);
            hg[p] = h;
            lg[p] = cvt_pk_bf16(l0, l1);
        }
        const int row = col0 + rr;
        short* sl = sldsA + row * 64;
        const int so = ((cg ^ ((row ^ (row >> 3)) & 7)) << 3);
        *(u32x4*)(sl + so) = hg;
        *(u32x4*)(sl + (so ^ 32)) = lg;
    }
    #pragma unroll
    for (int j = 0; j < 8; ++j)
        v[j] = *(const float4*)(sp + ((size_t)(BK + (cg << 3) + j) << 10));
    __syncthreads();

    // ---- main loop: one barrier per K-step ----
    // body(t): cvt v(t+1)->buf-next, MFMA(t) from buf-cur, load(t+2)->v
    for (int k0 = 0; k0 < CDIM; k0 += 2 * BK) {
        KSTEP(k0 + 2 * BK, WtA, XtA, sldsB);
        KSTEP(k0 + 3 * BK, WtB, XtB, sldsA);
    }

    // epilogue: C/D col = lane&15 (t), row = (lane>>4)*4 + q (d)
    float* __restrict__ oB = out + (size_t)b * (DDIM * TDIM)
                           + (size_t)(dtile + wdOff) * TDIM + (ttile + wtOff);
    #pragma unroll
    for (int m = 0; m < 4; ++m) {
        #pragma unroll
        for (int q = 0; q < 4; ++q) {
            const int d = m * 16 + (fg << 2) + q;
            float* orow = oB + (size_t)d * TDIM;
            #pragma unroll
            for (int n = 0; n < 8; ++n) {
                orow[n * 16 + fr] = acc[m][n][q];
            }
        }
    }
}

extern "C" void kernel_launch(void* const* d_in, const int* in_sizes, int n_in,
                              void* d_out, int out_size, void* d_ws, size_t ws_size,
                              hipStream_t stream) {
    const float* x = (const float*)d_in[0];
    const int* subjects = (const int*)d_in[1];
    const float* w = (const float*)d_in[2];
    float* out = (float*)d_out;
    subject_gemm<<<dim3(1024), dim3(512), 0, stream>>>(x, subjects, w, out);
}